// Round 5
// baseline (1371.523 us; speedup 1.0000x reference)
//
#include <hip/hip_runtime.h>
#include <hip/hip_bf16.h>
#include <math.h>

#define Bq 16
#define Tq 256
#define Hq 512
#define Vq 32000
#define Gq 1536
#define NWG 16

typedef __attribute__((ext_vector_type(8))) short short8;
typedef __attribute__((ext_vector_type(4))) float f32x4;

typedef const __attribute__((address_space(1))) void g_void;
typedef __attribute__((address_space(3))) void l_void;

__device__ __forceinline__ unsigned short f2bf(float f) {
    union { float f; unsigned int u; } v; v.f = f;
    unsigned int r = v.u + 0x7fffu + ((v.u >> 16) & 1u);
    return (unsigned short)(r >> 16);
}
__device__ __forceinline__ float bf2f(unsigned short h) {
    union { unsigned int u; float f; } v; v.u = ((unsigned int)h) << 16;
    return v.f;
}
// fast gates: v_exp-based, ~1e-6 rel err (far below bf16 noise)
__device__ __forceinline__ float sigm(float x) { return 1.0f / (1.0f + __expf(-x)); }
__device__ __forceinline__ float tanh_fast(float x) {
    float e = __expf(-2.0f * x);
    return (1.0f - e) / (1.0f + e);
}

// ---------------------------------------------------------------------------
// prep: cast E->bf16; split W_ih/W_hh into bf16 hi/lo; ZERO all Hpk stamps
// (so stale/garbage ws contents can never satisfy a poll this launch)
// ---------------------------------------------------------------------------
__global__ void prep_kernel(const float* __restrict__ E, const float* __restrict__ Wih,
                            const float* __restrict__ Whh,
                            unsigned short* __restrict__ Ebf,
                            unsigned short* __restrict__ WihHi, unsigned short* __restrict__ WihLo,
                            unsigned short* __restrict__ WhhHi, unsigned short* __restrict__ WhhLo,
                            unsigned long long* __restrict__ Hpk) {
    long tid = (long)blockIdx.x * blockDim.x + threadIdx.x;
    long stride = (long)gridDim.x * blockDim.x;
    for (long i = tid; i < (long)Vq * Hq; i += stride) Ebf[i] = f2bf(E[i]);
    for (long i = tid; i < (long)Gq * Hq; i += stride) {
        float w = Wih[i]; unsigned short hi = f2bf(w);
        WihHi[i] = hi; WihLo[i] = f2bf(w - bf2f(hi));
        w = Whh[i]; hi = f2bf(w);
        WhhHi[i] = hi; WhhLo[i] = f2bf(w - bf2f(hi));
    }
    for (long i = tid; i < (long)Tq * 8192; i += stride) Hpk[i] = 0ull;
}

// ---------------------------------------------------------------------------
// gi: gi_all[t,b,:] = E[tok(t,b)] @ W_ih^T + b_ih   (split-bf16, ~fp32 faithful)
// ---------------------------------------------------------------------------
__launch_bounds__(384)
__global__ void gi_kernel(const int* __restrict__ target, const float* __restrict__ E,
                          const unsigned short* __restrict__ WihHi,
                          const unsigned short* __restrict__ WihLo,
                          const float* __restrict__ b_ih, float* __restrict__ gi_all) {
    __shared__ __align__(16) unsigned short Ahi[16][520];
    __shared__ __align__(16) unsigned short Alo[16][520];
    __shared__ int toks[16];
    int t = blockIdx.x, gb = blockIdx.y;
    int tid = threadIdx.x;
    if (tid < 16) toks[tid] = (t == 0) ? 1 : target[tid * Tq + (t - 1)];  // START=1
    __syncthreads();
    for (int idx = tid; idx < 16 * Hq; idx += 384) {
        int r = idx >> 9, k = idx & 511;
        float v = E[(long)toks[r] * Hq + k];
        unsigned short hi = f2bf(v);
        Ahi[r][k] = hi; Alo[r][k] = f2bf(v - bf2f(hi));
    }
    __syncthreads();
    int wave = tid >> 6, lane = tid & 63;
    int gcb = gb * 96 + wave * 16;
    int row = lane & 15, kg = (lane >> 4) * 8;
    const unsigned short* bh = WihHi + (long)(gcb + row) * Hq;
    const unsigned short* bl = WihLo + (long)(gcb + row) * Hq;
    f32x4 aHH = {0,0,0,0}, aHL = {0,0,0,0}, aLH = {0,0,0,0};
#pragma unroll
    for (int ks = 0; ks < 16; ++ks) {
        int k0 = ks * 32 + kg;
        short8 ah = *(const short8*)&Ahi[row][k0];
        short8 al = *(const short8*)&Alo[row][k0];
        short8 wh = *(const short8*)&bh[k0];
        short8 wl = *(const short8*)&bl[k0];
        aHH = __builtin_amdgcn_mfma_f32_16x16x32_bf16(ah, wh, aHH, 0, 0, 0);
        aHL = __builtin_amdgcn_mfma_f32_16x16x32_bf16(ah, wl, aHL, 0, 0, 0);
        aLH = __builtin_amdgcn_mfma_f32_16x16x32_bf16(al, wh, aLH, 0, 0, 0);
    }
    int g = gcb + row;
    float bi = b_ih[g];
#pragma unroll
    for (int q = 0; q < 4; ++q) {
        int b = (lane >> 4) * 4 + q;
        gi_all[((long)(t * 16 + b)) * Gq + g] = aHH[q] + aHL[q] + aLH[q] + bi;
    }
}

// ---------------------------------------------------------------------------
// rnn: 16 WGs, 256 sequential steps. Self-validating h exchange: each u64
// word = [stamp=t+1 :32 | h_hi:bf16 | h_lo:bf16]. A fresh stamp proves the
// data in the SAME single-copy-atomic word is fresh -> zero ordering cost,
// ONE coherent RTT per step instead of three (drain + flag + load).
// ---------------------------------------------------------------------------
__launch_bounds__(384, 1)
__global__ void rnn_kernel(const float* __restrict__ h0,
                           const unsigned short* __restrict__ WhhHi,
                           const unsigned short* __restrict__ WhhLo,
                           const float* __restrict__ b_hh, const float* __restrict__ gi_all,
                           unsigned long long* Hpk, unsigned short* __restrict__ H_bf) {
    __shared__ __align__(16) unsigned short Ahi[16][520];
    __shared__ __align__(16) unsigned short Alo[16][520];
    __shared__ float gbuf[4][16][33];  // r_pre, z_pre, i_n, h_n
    int w = blockIdx.x, tid = threadIdx.x;
    int wave = tid >> 6, lane = tid & 63;
    int gate = wave >> 1;                            // 0:r 1:z 2:n
    int gcol = gate * 512 + w * 32 + (wave & 1) * 16;
    int row = lane & 15, kg = (lane >> 4) * 8;
    const unsigned short* bhp = WhhHi + (long)(gcol + row) * Hq;
    const unsigned short* blp = WhhLo + (long)(gcol + row) * Hq;
    short8 Bh[16], Bl[16];                           // stationary W_hh frags
#pragma unroll
    for (int ks = 0; ks < 16; ++ks) {
        Bh[ks] = *(const short8*)&bhp[ks * 32 + kg];
        Bl[ks] = *(const short8*)&blp[ks * 32 + kg];
    }
    float bhh = b_hh[gcol + row];
    float gin[4];
#pragma unroll
    for (int q = 0; q < 4; ++q) {
        int b = (lane >> 4) * 4 + q;
        gin[q] = gi_all[(long)b * Gq + (gcol + row)];
    }
    for (int t = 0; t < Tq; ++t) {
        // ---- acquire h_{t-1}: poll self-validating words, unpack to LDS ----
        if (t == 0) {
            for (int idx = tid; idx < Bq * Hq; idx += 384) {
                float v = h0[idx];
                unsigned short hi = f2bf(v);
                Ahi[idx >> 9][idx & 511] = hi;
                Alo[idx >> 9][idx & 511] = f2bf(v - bf2f(hi));
            }
        } else {
            const unsigned long long* src = Hpk + (long)(t - 1) * 8192;
            unsigned long long vb[22];
            bool ok;
            int guard = 0;
            do {
                ok = true;
#pragma unroll
                for (int k = 0; k < 21; ++k)
                    vb[k] = __hip_atomic_load(&src[tid + k * 384], __ATOMIC_RELAXED,
                                              __HIP_MEMORY_SCOPE_AGENT);
                if (tid < 128)
                    vb[21] = __hip_atomic_load(&src[8064 + tid], __ATOMIC_RELAXED,
                                               __HIP_MEMORY_SCOPE_AGENT);
                else
                    vb[21] = (unsigned long long)(unsigned int)t << 32;  // auto-pass
#pragma unroll
                for (int k = 0; k < 22; ++k)
                    ok = ok && ((int)(vb[k] >> 32) == t);
            } while (!ok && ++guard < 8192);   // bounded: no hangs, ever
#pragma unroll
            for (int k = 0; k < 21; ++k) {
                int i = tid + k * 384;
                unsigned int d = (unsigned int)vb[k];
                Ahi[i >> 9][i & 511] = (unsigned short)(d >> 16);
                Alo[i >> 9][i & 511] = (unsigned short)d;
            }
            if (tid < 128) {
                int i = 8064 + tid;
                unsigned int d = (unsigned int)vb[21];
                Ahi[i >> 9][i & 511] = (unsigned short)(d >> 16);
                Alo[i >> 9][i & 511] = (unsigned short)d;
            }
        }
        __syncthreads();
        // ---- gh = h @ Whh^T: split-bf16, 6 independent MFMA chains ----
        f32x4 xHH = {0,0,0,0}, xHL = {0,0,0,0}, xLH = {0,0,0,0};
        f32x4 yHH = {0,0,0,0}, yHL = {0,0,0,0}, yLH = {0,0,0,0};
#pragma unroll
        for (int ks = 0; ks < 8; ++ks) {
            int k0 = ks * 32 + kg;
            short8 ah = *(const short8*)&Ahi[row][k0];
            short8 al = *(const short8*)&Alo[row][k0];
            xHH = __builtin_amdgcn_mfma_f32_16x16x32_bf16(ah, Bh[ks], xHH, 0, 0, 0);
            xHL = __builtin_amdgcn_mfma_f32_16x16x32_bf16(ah, Bl[ks], xHL, 0, 0, 0);
            xLH = __builtin_amdgcn_mfma_f32_16x16x32_bf16(al, Bh[ks], xLH, 0, 0, 0);
        }
#pragma unroll
        for (int ks = 8; ks < 16; ++ks) {
            int k0 = ks * 32 + kg;
            short8 ah = *(const short8*)&Ahi[row][k0];
            short8 al = *(const short8*)&Alo[row][k0];
            yHH = __builtin_amdgcn_mfma_f32_16x16x32_bf16(ah, Bh[ks], yHH, 0, 0, 0);
            yHL = __builtin_amdgcn_mfma_f32_16x16x32_bf16(ah, Bl[ks], yHL, 0, 0, 0);
            yLH = __builtin_amdgcn_mfma_f32_16x16x32_bf16(al, Bh[ks], yLH, 0, 0, 0);
        }
        int jj = (wave & 1) * 16 + row;
#pragma unroll
        for (int q = 0; q < 4; ++q) {
            int b = (lane >> 4) * 4 + q;
            float ghv = (xHH[q] + yHH[q]) + (xHL[q] + yHL[q]) + (xLH[q] + yLH[q]) + bhh;
            if (gate < 2) gbuf[gate][b][jj] = ghv + gin[q];
            else { gbuf[2][b][jj] = gin[q]; gbuf[3][b][jj] = ghv; }
        }
        __syncthreads();
        // ---- gates + h_new; store stamped words (relaxed, no drain needed) ----
        if (tid < 256) {
            int b = tid >> 4, jp = tid & 15;
            int j0 = jp * 2, j1 = j0 + 1;
            int jc0 = w * 32 + j0;
            float r0 = sigm(gbuf[0][b][j0]);
            float z0 = sigm(gbuf[1][b][j0]);
            float n0 = tanh_fast(gbuf[2][b][j0] + r0 * gbuf[3][b][j0]);
            float hp0 = bf2f(Ahi[b][jc0]) + bf2f(Alo[b][jc0]);
            float hn0 = (1.0f - z0) * n0 + z0 * hp0;
            float r1 = sigm(gbuf[0][b][j1]);
            float z1 = sigm(gbuf[1][b][j1]);
            float n1 = tanh_fast(gbuf[2][b][j1] + r1 * gbuf[3][b][j1]);
            float hp1 = bf2f(Ahi[b][jc0 + 1]) + bf2f(Alo[b][jc0 + 1]);
            float hn1 = (1.0f - z1) * n1 + z1 * hp1;
            unsigned short h0h = f2bf(hn0), h1h = f2bf(hn1);
            unsigned short h0l = f2bf(hn0 - bf2f(h0h)), h1l = f2bf(hn1 - bf2f(h1h));
            unsigned long long stamp = (unsigned long long)(unsigned int)(t + 1) << 32;
            long i0 = (long)t * 8192 + b * 512 + jc0;
            __hip_atomic_store(&Hpk[i0], stamp | ((unsigned int)h0h << 16) | h0l,
                               __ATOMIC_RELAXED, __HIP_MEMORY_SCOPE_AGENT);
            __hip_atomic_store(&Hpk[i0 + 1], stamp | ((unsigned int)h1h << 16) | h1l,
                               __ATOMIC_RELAXED, __HIP_MEMORY_SCOPE_AGENT);
            *(unsigned int*)&H_bf[((long)(t * 16 + b)) * Hq + jc0] =
                ((unsigned int)h1h << 16) | h0h;
        }
        // gi prefetch for t+1 (rides across the barrier / next poll)
        int tp = (t + 1 < Tq) ? (t + 1) : t;
#pragma unroll
        for (int q = 0; q < 4; ++q) {
            int b = (lane >> 4) * 4 + q;
            gin[q] = gi_all[((long)(tp * 16 + b)) * Gq + (gcol + row)];
        }
        __syncthreads();  // protects Ahi/gbuf reuse for next iteration
    }
}

// ---------------------------------------------------------------------------
// logits: out[b,t,v] = H[t,b,:] @ E[v,:] + b_out[v]
// m97 structure: 128x128 tile, BK=64, global_load_lds w16, XOR-swizzled LDS
// (pre-swizzled global source, rule #21), 4 waves each 64x64, 32 MFMA/K-step.
// ---------------------------------------------------------------------------
__launch_bounds__(256)
__global__ void logits_kernel(const unsigned short* __restrict__ Hbf,
                              const unsigned short* __restrict__ Ebf,
                              const float* __restrict__ b_out, float* __restrict__ out) {
    __shared__ __align__(16) unsigned short As[128 * 64];
    __shared__ __align__(16) unsigned short Bs[128 * 64];
    int bid = blockIdx.x;
    int mb = bid & 31, nb = bid >> 5;     // M fastest: 32 mb-blocks share E-slice in L2
    int m0 = mb * 128, n0 = nb * 128;
    int tid = threadIdx.x;
    int wid = tid >> 6, lane = tid & 63;
    int wr = wid >> 1, wc = wid & 1;       // 2x2 wave grid, 64x64 per wave
    int rA = lane >> 3;
    int slp = (lane & 7) ^ rA;
    const unsigned short* gA = Hbf + (long)(m0 + wid * 8 + rA) * Hq + slp * 8;
    const unsigned short* gB = Ebf + (long)(n0 + wid * 8 + rA) * Hq + slp * 8;
    unsigned short* ldsA = As + wid * 512;
    unsigned short* ldsB = Bs + wid * 512;
    int fr = lane & 15, r7 = lane & 7, sb = lane >> 4;
    int Ra = wr * 64 + fr, Rb = wc * 64 + fr;
    f32x4 acc[4][4] = {};
    for (int kt = 0; kt < 8; ++kt) {
        if (kt) __syncthreads();
        int ko = kt * 64;
#pragma unroll
        for (int i = 0; i < 4; ++i) {
            __builtin_amdgcn_global_load_lds((g_void*)(gA + (long)i * 32 * Hq + ko),
                                             (l_void*)(ldsA + i * 2048), 16, 0, 0);
            __builtin_amdgcn_global_load_lds((g_void*)(gB + (long)i * 32 * Hq + ko),
                                             (l_void*)(ldsB + i * 2048), 16, 0, 0);
        }
        __syncthreads();
#pragma unroll
        for (int ks = 0; ks < 2; ++ks) {
            short8 af[4], bf[4];
#pragma unroll
            for (int f = 0; f < 4; ++f) {
                int Rr = Ra + f * 16;
                af[f] = *(const short8*)&As[Rr * 64 + (((sb + ks * 4) ^ r7) << 3)];
                int Rc = Rb + f * 16;
                bf[f] = *(const short8*)&Bs[Rc * 64 + (((sb + ks * 4) ^ r7) << 3)];
            }
#pragma unroll
            for (int fm = 0; fm < 4; ++fm)
#pragma unroll
                for (int fn = 0; fn < 4; ++fn)
                    acc[fm][fn] = __builtin_amdgcn_mfma_f32_16x16x32_bf16(
                        af[fm], bf[fn], acc[fm][fn], 0, 0, 0);
        }
    }
#pragma unroll
    for (int fn = 0; fn < 4; ++fn) {
        int v = n0 + wc * 64 + fn * 16 + fr;
        float bo = b_out[v];
#pragma unroll
        for (int fm = 0; fm < 4; ++fm) {
#pragma unroll
            for (int q = 0; q < 4; ++q) {
                int m = m0 + wr * 64 + fm * 16 + (lane >> 4) * 4 + q;
                out[((long)(m & 15) * Tq + (m >> 4)) * Vq + v] = acc[fm][fn][q] + bo;
            }
        }
    }
}

// ---------------------------------------------------------------------------
extern "C" void kernel_launch(void* const* d_in, const int* in_sizes, int n_in,
                              void* d_out, int out_size, void* d_ws, size_t ws_size,
                              hipStream_t stream) {
    const float* h0    = (const float*)d_in[0];
    const int*   target= (const int*)d_in[1];
    const float* E     = (const float*)d_in[2];
    const float* Wih   = (const float*)d_in[3];
    const float* Whh   = (const float*)d_in[4];
    const float* b_ih  = (const float*)d_in[5];
    const float* b_hh  = (const float*)d_in[6];
    const float* b_out = (const float*)d_in[7];
    float* out = (float*)d_out;

    char* ws = (char*)d_ws;
    size_t off = 0;
    unsigned short* Ebf   = (unsigned short*)(ws + off); off += (size_t)Vq * Hq * 2;
    unsigned short* WihHi = (unsigned short*)(ws + off); off += (size_t)Gq * Hq * 2;
    unsigned short* WihLo = (unsigned short*)(ws + off); off += (size_t)Gq * Hq * 2;
    unsigned short* WhhHi = (unsigned short*)(ws + off); off += (size_t)Gq * Hq * 2;
    unsigned short* WhhLo = (unsigned short*)(ws + off); off += (size_t)Gq * Hq * 2;
    float*          gi_all= (float*)(ws + off);          off += (size_t)Tq * Bq * Gq * 4;
    unsigned long long* Hpk = (unsigned long long*)(ws + off); off += (size_t)Tq * 8192 * 8;
    unsigned short* Hbf   = (unsigned short*)(ws + off); off += (size_t)Tq * Bq * Hq * 2;

    prep_kernel<<<dim3(2048), dim3(256), 0, stream>>>(E, Wih, Whh, Ebf, WihHi, WihLo,
                                                      WhhHi, WhhLo, Hpk);
    gi_kernel<<<dim3(Tq, 16), dim3(384), 0, stream>>>(target, E, WihHi, WihLo, b_ih, gi_all);
    rnn_kernel<<<dim3(NWG), dim3(384), 0, stream>>>(h0, WhhHi, WhhLo, b_hh, gi_all,
                                                    Hpk, Hbf);
    logits_kernel<<<dim3(32 * 250), dim3(256), 0, stream>>>(Hbf, Ebf, b_out, out);
}